// Round 3
// baseline (27.620 us; speedup 1.0000x reference)
//
#include <hip/hip_runtime.h>

#define TT 2048
#define BB 4096
#define DROP_ROWS 11
#define PERIOD 24
#define BLOCK 256
#define HALF 12
#define WAVES (BLOCK / 64)

__global__ __launch_bounds__(BLOCK) void seasonal_decomp_kernel(
    const float* __restrict__ x, float* __restrict__ out) {
  __shared__ float cs[TT + 1];         // exclusive cumsum (2049 floats)
  __shared__ float rc[32];             // 1/n LUT for window counts
  __shared__ float wt0[WAVES], wt1[WAVES];
  __shared__ float pp[PERIOD][8];
  __shared__ float pmean[PERIOD];

  const int tid = threadIdx.x;
  const int lane = tid & 63;
  const int wave = tid >> 6;
  const int row = blockIdx.x + DROP_ROWS;

  if (tid < 32) rc[tid] = 1.0f / (float)(tid ? tid : 1);

  // ---- coalesced load: two float4 per thread ----
  const float4* rx = (const float4*)(x + (size_t)row * TT);
  float4 v0 = rx[tid];          // elements [4*tid .. 4*tid+3]
  float4 v1 = rx[tid + 256];    // elements [1024+4*tid ..]

  // ---- hierarchical exclusive cumsum into cs ----
  float s0 = v0.x + v0.y + v0.z + v0.w;
  float s1 = v1.x + v1.y + v1.z + v1.w;
  float i0 = s0, i1 = s1;
  #pragma unroll
  for (int off = 1; off < 64; off <<= 1) {
    float t0 = __shfl_up(i0, off, 64);
    float t1 = __shfl_up(i1, off, 64);
    if (lane >= off) { i0 += t0; i1 += t1; }
  }
  if (lane == 63) { wt0[wave] = i0; wt1[wave] = i1; }
  __syncthreads();                       // --- barrier A1 (wave totals)
  float W0 = 0.f, W1 = 0.f, H = 0.f;
  #pragma unroll
  for (int w = 0; w < WAVES; ++w) {
    float a = wt0[w], b = wt1[w];
    H += a;
    if (w < wave) { W0 += a; W1 += b; }
  }
  const float P0 = W0 + (i0 - s0);       // cs[4*tid]
  const float P1 = H + W1 + (i1 - s1);   // cs[1024 + 4*tid]

  float4 c0, c1;
  c0.x = P0; c0.y = P0 + v0.x; c0.z = c0.y + v0.y; c0.w = c0.z + v0.z;
  c1.x = P1; c1.y = P1 + v1.x; c1.z = c1.y + v1.y; c1.w = c1.z + v1.z;
  ((float4*)cs)[tid] = c0;
  ((float4*)cs)[tid + 256] = c1;
  if (tid == 255) cs[TT] = P1 + s1;
  __syncthreads();                       // --- barrier A2 (cs ready)

  // ---- per-phase partial sums of detrended, straight from cs ----
  if (tid < PERIOD * 8) {
    int p = tid >> 3;
    int j = tid & 7;
    int cnt = (p < 8) ? 86 : 85;         // 2048 = 85*24 + 8
    float s = 0.f;
    for (int m = j; m < cnt; m += 8) {
      int t = p + PERIOD * m;
      int a = t - HALF; if (a < 0) a = 0;
      int e = t + HALF + 1; if (e > TT) e = TT;
      float tr = (cs[e] - cs[a]) * rc[e - a];
      float xt = cs[t + 1] - cs[t];
      s += xt - tr;
    }
    pp[p][j] = s;
  }
  __syncthreads();                       // --- barrier B
  if (tid < PERIOD) {
    float s = 0.f;
    #pragma unroll
    for (int j = 0; j < 8; ++j) s += pp[tid][j];
    pmean[tid] = s * ((tid < 8) ? (1.0f / 86.0f) : (1.0f / 85.0f));
  }
  __syncthreads();                       // --- barrier C

  // ---- epilogue: each thread owns 6 OUTPUT float4s (coalesced) ----
  float4* orow = (float4*)(out + (size_t)blockIdx.x * (TT * 3));
  #pragma unroll
  for (int j = 0; j < 6; ++j) {
    int g = tid + 256 * j;
    int f0 = 4 * g;
    int t0 = f0 / 3;                     // magic-mul
    int r = f0 - 3 * t0;                 // component phase 0/1/2
    // decompose t0 and t0+1 (t0+1 <= 2047 always)
    float tr0, se0, re0, tr1, se1, re1;
    {
      int t = t0;
      int a = t - HALF; if (a < 0) a = 0;
      int e = t + HALF + 1; if (e > TT) e = TT;
      tr0 = (cs[e] - cs[a]) * rc[e - a];
      float xt = cs[t + 1] - cs[t];
      se0 = pmean[t % PERIOD];
      re0 = xt - tr0 - se0;
    }
    {
      int t = t0 + 1;
      int a = t - HALF; if (a < 0) a = 0;
      int e = t + HALF + 1; if (e > TT) e = TT;
      tr1 = (cs[e] - cs[a]) * rc[e - a];
      float xt = cs[t + 1] - cs[t];
      se1 = pmean[t % PERIOD];
      re1 = xt - tr1 - se1;
    }
    float4 v;
    v.x = (r == 0) ? tr0 : ((r == 1) ? se0 : re0);
    v.y = (r == 0) ? se0 : ((r == 1) ? re0 : tr1);
    v.z = (r == 0) ? re0 : ((r == 1) ? tr1 : se1);
    v.w = (r == 0) ? tr1 : ((r == 1) ? se1 : re1);
    orow[g] = v;
  }
}

extern "C" void kernel_launch(void* const* d_in, const int* in_sizes, int n_in,
                              void* d_out, int out_size, void* d_ws, size_t ws_size,
                              hipStream_t stream) {
  const float* x = (const float*)d_in[0];
  float* out = (float*)d_out;
  seasonal_decomp_kernel<<<BB - DROP_ROWS, BLOCK, 0, stream>>>(x, out);
}

// Round 4
// 27.577 us; speedup vs baseline: 1.0016x; 1.0016x over previous
//
#include <hip/hip_runtime.h>

#define TT 2048
#define BB 4096
#define DROP_ROWS 11
#define NOUT (BB - DROP_ROWS)   /* 4085 output rows */
#define PERIOD 24
#define BLOCK 256
#define HALF 12
#define ROWS 4

__global__ __launch_bounds__(BLOCK) void seasonal_decomp_kernel(
    const float* __restrict__ x, float* __restrict__ out) {
  // Overlay (disjoint lifetimes):
  //   cs   = buf[0..2048]    exclusive cumsum          (scan -> trend)
  //   sd   = buf[2080..4127] detrended row             (trend -> phase sums)
  //   sout = buf[0..6143]    packed output row         (pack -> store)
  __shared__ float buf[6144];
  __shared__ float wt0[4], wt1[4];
  __shared__ float pp[PERIOD][8];
  __shared__ float pmean[PERIOD];
  float* const cs = buf;
  float* const sd = buf + 2080;
  float* const sout = buf;

  const int tid = threadIdx.x;
  const int lane = tid & 63;
  const int wave = tid >> 6;
  const int rbase = blockIdx.x * ROWS;

  // initial prefetch of first row
  float4 v0, v1;
  if (rbase < NOUT) {
    const float4* rx = (const float4*)(x + (size_t)(rbase + DROP_ROWS) * TT);
    v0 = rx[tid];
    v1 = rx[tid + 256];
  }

  for (int r = 0; r < ROWS; ++r) {
    const int orow_i = rbase + r;
    const bool active = (orow_i < NOUT);   // uniform per block

    float s0 = 0.f, s1 = 0.f, i0 = 0.f, i1 = 0.f;
    float tr[8], sdr[8];

    if (active) {
      // ---- wave-level inclusive scan of per-thread chunk sums ----
      s0 = v0.x + v0.y + v0.z + v0.w;
      s1 = v1.x + v1.y + v1.z + v1.w;
      i0 = s0; i1 = s1;
      #pragma unroll
      for (int off = 1; off < 64; off <<= 1) {
        float t0 = __shfl_up(i0, off, 64);
        float t1 = __shfl_up(i1, off, 64);
        if (lane >= off) { i0 += t0; i1 += t1; }
      }
      if (lane == 63) { wt0[wave] = i0; wt1[wave] = i1; }
    }
    __syncthreads();                       // A1: wt ready; prev row's buf reads done

    if (active) {
      float W0 = 0.f, W1 = 0.f, H = 0.f;
      #pragma unroll
      for (int w = 0; w < 4; ++w) {
        float a = wt0[w], b = wt1[w];
        H += a;
        if (w < wave) { W0 += a; W1 += b; }
      }
      const float P0 = W0 + (i0 - s0);     // cs[4*tid]
      const float P1 = H + W1 + (i1 - s1); // cs[1024 + 4*tid]
      float4 c0, c1;
      c0.x = P0; c0.y = P0 + v0.x; c0.z = c0.y + v0.y; c0.w = c0.z + v0.z;
      c1.x = P1; c1.y = P1 + v1.x; c1.z = c1.y + v1.y; c1.w = c1.z + v1.z;
      ((float4*)cs)[tid] = c0;
      ((float4*)cs)[tid + 256] = c1;
      if (tid == 255) cs[TT] = P1 + s1;
    }

    // ---- prefetch NEXT row into registers; flies under the whole back half ----
    if (r + 1 < ROWS && rbase + r + 1 < NOUT) {
      const float4* rx =
          (const float4*)(x + (size_t)(rbase + r + 1 + DROP_ROWS) * TT);
      v0 = rx[tid];
      v1 = rx[tid + 256];
    }
    __syncthreads();                       // A2: cs ready

    if (active) {
      // ---- trend + detrended; read2-fused LDS reads on the interior path ----
      #pragma unroll
      for (int j = 0; j < 8; ++j) {
        const int t = tid + 256 * j;
        const float* p = &cs[t];
        const float xt = p[1] - p[0];      // ds_read2_b32 (offsets 0,1)
        float trv;
        if (t >= HALF && t < TT - HALF - 1) {          // interior: count = 25
          const float* q = &cs[t - HALF];
          trv = (q[2 * HALF + 1] - q[0]) * (1.0f / 25.0f);  // read2 (0,25)
        } else {
          const int a = (t - HALF < 0) ? 0 : t - HALF;
          const int e = (t + HALF + 1 > TT) ? TT : t + HALF + 1;
          trv = (cs[e] - cs[a]) / (float)(e - a);
        }
        tr[j] = trv;
        sdr[j] = xt - trv;
        sd[t] = sdr[j];
      }
    }
    __syncthreads();                       // B: sd ready

    if (active && tid < PERIOD * 8) {
      const int p = tid >> 3, jj = tid & 7;
      const int cnt = (p < 8) ? 86 : 85;   // 2048 = 85*24 + 8
      float s = 0.f;
      for (int m = jj; m < cnt; m += 8) s += sd[p + PERIOD * m];
      pp[p][jj] = s;
    }
    __syncthreads();                       // C: pp ready

    if (active && tid < PERIOD) {
      float s = 0.f;
      #pragma unroll
      for (int j2 = 0; j2 < 8; ++j2) s += pp[tid][j2];
      pmean[tid] = s * ((tid < 8) ? (1.0f / 86.f) : (1.0f / 85.f));
    }
    __syncthreads();                       // D: pmean ready; cs/sd dead

    if (active) {
      // ---- pack row into LDS (stride-3 b32 writes = 2 lanes/bank, free) ----
      int ph = tid % PERIOD;
      #pragma unroll
      for (int j = 0; j < 8; ++j) {
        const int t = tid + 256 * j;
        const float pm = pmean[ph];
        ph += 16; if (ph >= PERIOD) ph -= PERIOD;   // (t+256) % 24
        sout[3 * t]     = tr[j];
        sout[3 * t + 1] = pm;
        sout[3 * t + 2] = sdr[j] - pm;
      }
    }
    __syncthreads();                       // E: sout ready

    if (active) {
      // ---- fully-coalesced float4 stores ----
      float4* orow = (float4*)(out + (size_t)orow_i * (TT * 3));
      const float4* so4 = (const float4*)sout;
      #pragma unroll
      for (int j = 0; j < 6; ++j) orow[tid + 256 * j] = so4[tid + 256 * j];
    }
  }
}

extern "C" void kernel_launch(void* const* d_in, const int* in_sizes, int n_in,
                              void* d_out, int out_size, void* d_ws, size_t ws_size,
                              hipStream_t stream) {
  const float* x = (const float*)d_in[0];
  float* out = (float*)d_out;
  const int grid = (NOUT + ROWS - 1) / ROWS;   // 1022 blocks -> ~4 per CU, all resident
  seasonal_decomp_kernel<<<grid, BLOCK, 0, stream>>>(x, out);
}

// Round 5
// 26.891 us; speedup vs baseline: 1.0271x; 1.0255x over previous
//
#include <hip/hip_runtime.h>

#define TT 2048
#define BB 4096
#define DROP_ROWS 11
#define NOUT (BB - DROP_ROWS)   /* 4085 output rows */
#define PERIOD 24
#define BLOCK 256
#define HALF 12
#define ROWS 4

__global__ __launch_bounds__(BLOCK) void seasonal_decomp_kernel(
    const float* __restrict__ x, float* __restrict__ out) {
  // buf overlays: cs[0..2048] (cumsum) then sout[0..6143] (packed output).
  // cs is dead after trend; pack starts after barrier D.
  __shared__ float buf[6144];
  __shared__ float pp2[3][264];        // +8 pad -> reducer reads conflict-free
  __shared__ float wt0[4], wt1[4];
  __shared__ float pmean[PERIOD];
  float* const cs = buf;
  float* const sout = buf;

  const int tid = threadIdx.x;
  const int lane = tid & 63;
  const int wave = tid >> 6;
  const int rbase = blockIdx.x * ROWS;

  // per-thread constants (invariant across rows)
  const int q0 = (512 * wave + lane) % 24;   // phase of this thread's j=0 element
  int mA, mB, mC;                            // phase-slot (p>>3) for groups A,B,C
  if (q0 < 8)       { mA = 0; mB = 2; mC = 1; }
  else if (q0 < 16) { mA = 1; mB = 0; mC = 2; }
  else              { mA = 2; mB = 1; mC = 0; }

  // initial prefetch of first row (thread owns x[4tid..] and x[1024+4tid..])
  float4 v0, v1;
  if (rbase < NOUT) {
    const float4* rx = (const float4*)(x + (size_t)(rbase + DROP_ROWS) * TT);
    v0 = rx[tid];
    v1 = rx[tid + 256];
  }

  for (int r = 0; r < ROWS; ++r) {
    const int orow_i = rbase + r;
    const bool active = (orow_i < NOUT);     // uniform per block

    float s0 = 0.f, s1 = 0.f, i0 = 0.f, i1 = 0.f;
    if (active) {
      // ---- wave-level inclusive scan of per-thread chunk sums ----
      s0 = v0.x + v0.y + v0.z + v0.w;
      s1 = v1.x + v1.y + v1.z + v1.w;
      i0 = s0; i1 = s1;
      #pragma unroll
      for (int off = 1; off < 64; off <<= 1) {
        float t0 = __shfl_up(i0, off, 64);
        float t1 = __shfl_up(i1, off, 64);
        if (lane >= off) { i0 += t0; i1 += t1; }
      }
      if (lane == 63) { wt0[wave] = i0; wt1[wave] = i1; }
    }
    __syncthreads();                         // A1: wt ready; prev row fully done

    if (active) {
      float W0 = 0.f, W1 = 0.f, H = 0.f;
      #pragma unroll
      for (int w = 0; w < 4; ++w) {
        float a = wt0[w], b = wt1[w];
        H += a;
        if (w < wave) { W0 += a; W1 += b; }
      }
      const float P0 = W0 + (i0 - s0);       // cs[4*tid]
      const float P1 = H + W1 + (i1 - s1);   // cs[1024 + 4*tid]
      float4 c0, c1;
      c0.x = P0; c0.y = P0 + v0.x; c0.z = c0.y + v0.y; c0.w = c0.z + v0.z;
      c1.x = P1; c1.y = P1 + v1.x; c1.z = c1.y + v1.y; c1.w = c1.z + v1.z;
      ((float4*)cs)[tid] = c0;
      ((float4*)cs)[tid + 256] = c1;
      if (tid == 255) cs[TT] = P1 + s1;
    }

    // ---- prefetch NEXT row; latency hides under trend/pack/store ----
    if (r + 1 < ROWS && rbase + r + 1 < NOUT) {
      const float4* rx =
          (const float4*)(x + (size_t)(rbase + r + 1 + DROP_ROWS) * TT);
      v0 = rx[tid];
      v1 = rx[tid + 256];
    }
    __syncthreads();                         // A2: cs ready

    float tr[8], sdr[8];
    if (active) {
      // ---- trend + detrended; per-wave chunk t = 512*wave + 64*j + lane ----
      // phase partials accumulate in registers (3 phases per thread)
      float A = 0.f, B = 0.f, C2 = 0.f;
      #pragma unroll
      for (int j = 0; j < 8; ++j) {
        const int t = 512 * wave + 64 * j + lane;
        const float xt = cs[t + 1] - cs[t];            // ds_read2
        float trv;
        if (t >= HALF && t < TT - HALF - 1) {          // interior: count 25
          trv = (cs[t + HALF + 1] - cs[t - HALF]) * (1.0f / 25.0f);
        } else {
          const int a = (t - HALF < 0) ? 0 : t - HALF;
          const int e = (t + HALF + 1 > TT) ? TT : t + HALF + 1;
          trv = (cs[e] - cs[a]) / (float)(e - a);
        }
        tr[j] = trv;
        sdr[j] = xt - trv;
        if (j % 3 == 0) A += sdr[j];        // phase q0
        else if (j % 3 == 1) B += sdr[j];   // phase (q0+16)%24
        else C2 += sdr[j];                  // phase (q0+8)%24
      }
      pp2[mA][tid] = A;
      pp2[mB][tid] = B;
      pp2[mC][tid] = C2;
    }
    __syncthreads();                         // C: pp2 ready (trend reads done)

    if (active && tid < PERIOD) {
      const int c = tid & 7, m = tid >> 3;   // phase = 8m + c
      float s = 0.f;
      #pragma unroll
      for (int k = 0; k < 32; ++k) s += pp2[m][8 * k + c];
      pmean[tid] = s * ((tid < 8) ? (1.0f / 86.f) : (1.0f / 85.f));
    }
    __syncthreads();                         // D: pmean ready; cs dead

    if (active) {
      // ---- wave-local pack (stride-3 writes: 2 lanes/bank = free) ----
      float* const mysout = sout + 1536 * wave;
      int p = q0;
      #pragma unroll
      for (int j = 0; j < 8; ++j) {
        const int t64 = 64 * j + lane;
        const float pm = pmean[p];
        p += 16; if (p >= PERIOD) p -= PERIOD;
        mysout[3 * t64]     = tr[j];
        mysout[3 * t64 + 1] = pm;
        mysout[3 * t64 + 2] = sdr[j] - pm;
      }
      // ---- wave-local read-back + coalesced float4 stores (no barrier) ----
      const float4* so4 = (const float4*)mysout;
      float4* orow = (float4*)(out + (size_t)orow_i * (TT * 3));
      #pragma unroll
      for (int j = 0; j < 6; ++j)
        orow[384 * wave + 64 * j + lane] = so4[64 * j + lane];
    }
  }
}

extern "C" void kernel_launch(void* const* d_in, const int* in_sizes, int n_in,
                              void* d_out, int out_size, void* d_ws, size_t ws_size,
                              hipStream_t stream) {
  const float* x = (const float*)d_in[0];
  float* out = (float*)d_out;
  const int grid = (NOUT + ROWS - 1) / ROWS;   // 1022 blocks, ~4/CU, all resident
  seasonal_decomp_kernel<<<grid, BLOCK, 0, stream>>>(x, out);
}